// Round 8
// baseline (237.337 us; speedup 1.0000x reference)
//
#include <hip/hip_runtime.h>
#include <cstdint>

// Fully-fused GRU: B=2048, T=256, F=64, H=32. fp32 in/out. ONE kernel.
// 256 blocks x 256 thr = 4 waves/block (r4 structure):
//   waves 2,3 (producers): ring x-loads, hi/lo bf16 split, 24 x-proj
//     MFMAs/group with BIASES AS C-INIT, write LDS (double-buffered,
//     conflict-light [col][gate] layout), one group (4 steps) ahead.
//   waves 0,1 (chains): recurrence, zero memory-latency ops on the chain;
//     per step 6 hh MFMAs + acts + 4x v_mov_dpp quad_perm B-frag all-gather.
// Round-8 change (TRANS-PIPE ELIMINATION): r4-r7 timings fit trans ops at
// ~45cy each (9/step = ~400cy = the dominant term; r5/r6 showed it is
// occupied pipe, not fillable stall). Replace exp-based sigmoid/tanh with
// odd Pade(7,6) rationals (|err|<1e-4 with clamp; 20x below bf16-h noise):
//   sigma(x) = clamp(0.5 + x*P(x^2)/Q(x^2), 0, 1),  tanh(v) = clamp(v*Pt/Qt,-1,1)
// and batch divisions: 4 sigmoid dens -> ONE v_rcp (product+recovery),
// 2 tanh dens (depend on r, separate) -> ONE v_rcp. 9 trans -> 2 trans/step.
// Biases move to producer C-init (b_ih+b_hh for r/z rows, b_ih for n rows);
// chain C-init: zero vector for r/z tiles, b_hh n-rows for n tiles.

#define TSEQ 256
#define CSTRIDE 104                                // floats per col (16B aligned)

typedef __attribute__((ext_vector_type(8))) short bf16x8;
typedef __attribute__((ext_vector_type(4))) float f32x4;
union BF8 { unsigned u[4]; bf16x8 v; };

__device__ __forceinline__ unsigned bfr(float f) {            // bf16 RNE in hi16
    unsigned u = __float_as_uint(f);
    return u + 0x7fffu + ((u >> 16) & 1u);
}
__device__ __forceinline__ unsigned packhi(unsigned a, unsigned b) {
    return __builtin_amdgcn_perm(b, a, 0x07060302u);          // hi16(a)|hi16(b)<<16
}
// 8 fp32 -> hi (truncated bf16) + lo (bf16 of residual): 3-term-quality products
__device__ __forceinline__ void cvt2(const float4& f0, const float4& f1,
                                     bf16x8& hi, bf16x8& lo) {
    float f[8] = {f0.x,f0.y,f0.z,f0.w, f1.x,f1.y,f1.z,f1.w};
    BF8 H, L;
    #pragma unroll
    for (int d = 0; d < 4; ++d) {
        float a = f[2*d], b = f[2*d+1];
        unsigned ua = __float_as_uint(a), ub = __float_as_uint(b);
        float ra = a - __uint_as_float(ua & 0xffff0000u);
        float rb = b - __uint_as_float(ub & 0xffff0000u);
        H.u[d] = packhi(ua, ub);
        L.u[d] = packhi(bfr(ra), bfr(rb));
    }
    hi = H.v; lo = L.v;
}
__device__ __forceinline__ float sel4(f32x4 v, int u) {
    float a = (u & 1) ? v[1] : v[0];
    float b = (u & 1) ? v[3] : v[2];
    return (u & 2) ? b : a;
}

// ---- odd Pade(7,6) rationals (tanh core), coefficients /135135 ----
// sigma(x) = 0.5 + 0.5*tanh(x/2) = 0.5 + x*Ps(x^2)/Qs(x^2)
__device__ __forceinline__ void sigr(float x, float& xnum, float& den) {
    float t = x * x;
    float n = __builtin_fmaf(__builtin_fmaf(__builtin_fmaf(
                  2.890625e-8f, t, 4.370629e-5f), t, 8.012821e-3f), t, 0.25f);
    den     = __builtin_fmaf(__builtin_fmaf(__builtin_fmaf(
                  3.237500e-6f, t, 1.456879e-3f), t, 0.11538462f), t, 1.0f);
    xnum = x * n;
}
// tanh(v) = v*Pt(v^2)/Qt(v^2)
__device__ __forceinline__ void tanr(float x, float& xnum, float& den) {
    float t = x * x;
    float n = __builtin_fmaf(__builtin_fmaf(__builtin_fmaf(
                  7.400300e-6f, t, 2.797203e-3f), t, 0.12820513f), t, 1.0f);
    den     = __builtin_fmaf(__builtin_fmaf(__builtin_fmaf(
                  2.071987e-4f, t, 2.331002e-2f), t, 0.46153846f), t, 1.0f);
    xnum = x * n;
}

#define MFMA16(A, B, C) __builtin_amdgcn_mfma_f32_16x16x32_bf16((A), (B), (C), 0, 0, 0)

// quad_perm broadcast of lane w within each aligned 4-lane quad (pure VALU).
#define QBCAST(x, w) ((unsigned)__builtin_amdgcn_update_dpp( \
        0, (int)(x), ((w) | ((w)<<2) | ((w)<<4) | ((w)<<6)), 0xf, 0xf, true))

// barrier WITHOUT the compiler's vmcnt(0) drain: producers' in-flight HBM
// prefetch (needed a full group later) survives the sync.
__device__ __forceinline__ void barrier_nodrain() {
    asm volatile("s_waitcnt lgkmcnt(0)" ::: "memory");
    __builtin_amdgcn_s_barrier();
    asm volatile("" ::: "memory");
}

__global__ __launch_bounds__(256, 1)
void gru_fused(const float* __restrict__ x, const float* __restrict__ W_ih,
               const float* __restrict__ W_hh, const float* __restrict__ b_ih,
               const float* __restrict__ b_hh, const float* __restrict__ W_head,
               const float* __restrict__ b_head, float* __restrict__ out)
{
    // [buf][quad][col*CSTRIDE + nt*16 + q*4 + r]; col = batch + 4*step
    __shared__ float xsh[2][2][16 * CSTRIDE];
    const int tid  = threadIdx.x;
    const int wid  = tid >> 6;                     // 0,1 = chain; 2,3 = producer
    const int lane = tid & 63;
    const int m = lane & 15, q = lane >> 4;
    const int b0 = blockIdx.x * 8;

    if (wid >= 2) {
        // ===================== producer (quad pq) =====================
        const int pq = wid - 2;
        const int bq = m & 3, u = m >> 2;          // col m = (batch bq, step u)
        bf16x8 Aih[6][2];
        #pragma unroll
        for (int nt = 0; nt < 6; ++nt)
            #pragma unroll
            for (int c = 0; c < 2; ++c) {
                const float* wp = W_ih + (nt*16 + m)*64 + c*32 + q*8;
                BF8 t;
                #pragma unroll
                for (int d = 0; d < 4; ++d) t.u[d] = packhi(bfr(wp[2*d]), bfr(wp[2*d+1]));
                Aih[nt][c] = t.v;
            }
        // bias C-init: rows nt*16+q*4+r. r/z tiles: b_ih+b_hh; n tiles: b_ih.
        f32x4 PC[6];
        #pragma unroll
        for (int nt = 0; nt < 6; ++nt) {
            f32x4 t;
            #pragma unroll
            for (int r = 0; r < 4; ++r) {
                int g = nt*16 + q*4 + r;
                t[r] = (nt < 4) ? (b_ih[g] + b_hh[g]) : b_ih[g];
            }
            PC[nt] = t;
        }
        float4 ring[4];
        const float* xcol = x + ((size_t)(b0 + pq*4 + bq)*TSEQ + u)*64 + q*8;
        auto ldring = [&](int grp) {
            const float* p = xcol + grp*256;       // grp*4 steps * 64 floats
            ring[0] = ((const float4*)p)[0];        ring[1] = ((const float4*)p)[1];
            ring[2] = ((const float4*)(p+32))[0];   ring[3] = ((const float4*)(p+32))[1];
        };
        auto projwrite = [&](int buf) {            // ring -> x-proj+bias -> LDS[buf]
            bf16x8 Xh0, Xl0, Xh1, Xl1;
            cvt2(ring[0], ring[1], Xh0, Xl0);
            cvt2(ring[2], ring[3], Xh1, Xl1);
            #pragma unroll
            for (int nt = 0; nt < 6; ++nt) {
                f32x4 a = MFMA16(Aih[nt][0], Xh0, PC[nt]);
                a = MFMA16(Aih[nt][0], Xl0, a);
                a = MFMA16(Aih[nt][1], Xh1, a);
                a = MFMA16(Aih[nt][1], Xl1, a);
                *(f32x4*)&xsh[buf][pq][m*CSTRIDE + nt*16 + q*4] = a;   // 16B aligned
            }
        };
        ldring(0);
        projwrite(0);                              // group-0 data into buf 0
        ldring(1);
        barrier_nodrain();                         // buf0 ready
        for (int g = 0; g < 64; ++g) {
            if (g < 63) {
                projwrite((g + 1) & 1);            // chain is in buf[g&1]
                ldring(g + 2 < 64 ? g + 2 : 63);
            }
            barrier_nodrain();
        }
    } else {
        // ===================== chain (quad cq) =====================
        const int cq = wid;
        const int bq = m >> 2, u = m & 3;          // replicas = consecutive lanes
        // ---- W_hh A-frags, K-permuted: pos p=q*8+j <-> dim (p>>1)+16*(p&1)
        bf16x8 Awh[6];
        #pragma unroll
        for (int nt = 0; nt < 6; ++nt) {
            const float* wp = W_hh + (nt*16 + m)*32;
            BF8 t;
            #pragma unroll
            for (int d = 0; d < 4; ++d) {
                int dd = q*4 + d;
                t.u[d] = packhi(bfr(wp[dd]), bfr(wp[dd + 16]));
            }
            Awh[nt] = t.v;
        }
        // ---- C-inits: zero for r/z tiles (bias now in producer), b_hh n-rows
        const f32x4 CZ = {0.f, 0.f, 0.f, 0.f};
        f32x4 BN0, BN1;
        #pragma unroll
        for (int r = 0; r < 4; ++r) { BN0[r] = b_hh[64+q*4+r]; BN1[r] = b_hh[80+q*4+r]; }

        unsigned Hd[4] = {0u, 0u, 0u, 0u};         // h B-frag dwords (bf16 pairs)
        float hOL = 0.f, hOH = 0.f;                // own h dims (q*4+u, +16), fp32
        barrier_nodrain();                         // buf0 ready

        for (int g = 0; g < 64; ++g) {
            const int cbuf = g & 1;
            // this group's x-pre scalars: 24 ds_read_b32, off the dep chain
            float xp[4][6];
            #pragma unroll
            for (int s = 0; s < 4; ++s) {
                const float* rp = &xsh[cbuf][cq][(bq + 4*s)*CSTRIDE + q*4 + u];
                #pragma unroll
                for (int nt = 0; nt < 6; ++nt) xp[s][nt] = rp[nt*16];
            }
            #pragma unroll
            for (int s = 0; s < 4; ++s) {
                BF8 bh; bh.u[0]=Hd[0]; bh.u[1]=Hd[1]; bh.u[2]=Hd[2]; bh.u[3]=Hd[3];
                f32x4 a0 = MFMA16(Awh[0], bh.v, CZ);
                f32x4 a1 = MFMA16(Awh[1], bh.v, CZ);
                f32x4 a2 = MFMA16(Awh[2], bh.v, CZ);
                f32x4 a3 = MFMA16(Awh[3], bh.v, CZ);
                f32x4 a4 = MFMA16(Awh[4], bh.v, BN0);
                f32x4 a5 = MFMA16(Awh[5], bh.v, BN1);

                // --- rational sigmoids (4 dens -> ONE rcp via product) ---
                float xnr0, dr0, xnr1, dr1, xnz0, dz0, xnz1, dz1;
                sigr(xp[s][0] + sel4(a0, u), xnr0, dr0);
                sigr(xp[s][1] + sel4(a1, u), xnr1, dr1);
                sigr(xp[s][2] + sel4(a2, u), xnz0, dz0);
                sigr(xp[s][3] + sel4(a3, u), xnz1, dz1);
                float p01 = dr0 * dr1, p23 = dz0 * dz1;
                float q4 = __builtin_amdgcn_rcpf(p01 * p23);
                float qa = q4 * p23, qb = q4 * p01;
                float r0 = fminf(fmaxf(__builtin_fmaf(xnr0, qa * dr1, 0.5f), 0.f), 1.f);
                float r1 = fminf(fmaxf(__builtin_fmaf(xnr1, qa * dr0, 0.5f), 0.f), 1.f);
                float z0 = fminf(fmaxf(__builtin_fmaf(xnz0, qb * dz1, 0.5f), 0.f), 1.f);
                float z1 = fminf(fmaxf(__builtin_fmaf(xnz1, qb * dz0, 0.5f), 0.f), 1.f);

                // --- rational tanh (2 dens -> ONE rcp) ---
                float v0 = __builtin_fmaf(r0, sel4(a4, u), xp[s][4]);
                float v1 = __builtin_fmaf(r1, sel4(a5, u), xp[s][5]);
                float xnt0, dt0, xnt1, dt1;
                tanr(v0, xnt0, dt0);
                tanr(v1, xnt1, dt1);
                float qt = __builtin_amdgcn_rcpf(dt0 * dt1);
                float t0 = fminf(fmaxf(xnt0 * (qt * dt1), -1.f), 1.f);
                float t1 = fminf(fmaxf(xnt1 * (qt * dt0), -1.f), 1.f);

                float hNL = __builtin_fmaf(z0, hOL - t0, t0);
                float hNH = __builtin_fmaf(z1, hOH - t1, t1);
                hOL = hNL; hOH = hNH;

                // B-frag all-gather within the 4-lane replica quad (VALU only).
                unsigned pk;
                asm("v_cvt_pk_bf16_f32 %0, %1, %2" : "=v"(pk) : "v"(hNL), "v"(hNH));
                Hd[0] = QBCAST(pk, 0);
                Hd[1] = QBCAST(pk, 1);
                Hd[2] = QBCAST(pk, 2);
                Hd[3] = QBCAST(pk, 3);
            }
            barrier_nodrain();
        }

        // ---- head: lane holds fp32 h dims (q*4+u, +16) of batch bq
        float v = hOL * W_head[q*4 + u] + hOH * W_head[16 + q*4 + u];
        v += __shfl_xor(v, 1, 64);                 // sum over u (lane bits 0,1)
        v += __shfl_xor(v, 2, 64);
        v += __shfl_xor(v, 16, 64);                // sum over q (lane bits 4,5)
        v += __shfl_xor(v, 32, 64);
        if (lane < 16 && (lane & 3) == 0) {
            float a = v + b_head[0];
            float e = __builtin_amdgcn_exp2f(-1.4426950408889634f * a);
            out[b0 + cq*4 + (lane >> 2)] = __builtin_amdgcn_rcpf(1.f + e);
        }
    }
}

extern "C" void kernel_launch(void* const* d_in, const int* in_sizes, int n_in,
                              void* d_out, int out_size, void* d_ws, size_t ws_size,
                              hipStream_t stream)
{
    const float* x      = (const float*)d_in[0];
    const float* W_ih   = (const float*)d_in[1];
    const float* W_hh   = (const float*)d_in[2];
    const float* b_ih   = (const float*)d_in[3];
    const float* b_hh   = (const float*)d_in[4];
    const float* W_head = (const float*)d_in[5];
    const float* b_head = (const float*)d_in[6];
    float* out = (float*)d_out;

    gru_fused<<<256, 256, 0, stream>>>(x, W_ih, W_hh, b_ih, b_hh,
                                       W_head, b_head, out);
}